// Round 1
// baseline (601.666 us; speedup 1.0000x reference)
//
#include <hip/hip_runtime.h>
#include <hip/hip_bf16.h>

#define RELU_NEG_SLOPE 0.2f

// ---------------------------------------------------------------------------
// Edge decode: src = concat(e0, e1, arange), dst = concat(e1, e0, arange)
// edges laid out row-major: edges[0..E0) = row0, edges[E0..2E0) = row1.
// For i in [0,E0):    src=edges[i],     dst=edges[E0+i]
// For i in [E0,2E0):  src=edges[i],     dst=edges[i-E0]
// For i >= 2E0:       src=dst=i-2E0
// ---------------------------------------------------------------------------
__device__ __forceinline__ void get_edge(const int* __restrict__ edges, int E0,
                                         int i, int& s, int& d) {
    if (i < 2 * E0) {
        s = edges[i];
        d = (i < E0) ? edges[E0 + i] : edges[i - E0];
    } else {
        s = d = i - 2 * E0;
    }
}

// ---------------------------------------------------------------------------
// B[d*512 + h*64 + f] = W1[h][d][f]  (W1 is (8,128,64) row-major)
// ---------------------------------------------------------------------------
__global__ void transform_w1(const float* __restrict__ W1, float* __restrict__ B,
                             int total) {
    int i = blockIdx.x * 256 + threadIdx.x;
    if (i >= total) return;
    int f = i & 63;
    int d = (i >> 6) & 127;
    int h = i >> 13;
    B[d * 512 + h * 64 + f] = W1[i];
}

// ---------------------------------------------------------------------------
// Generic fp32 tiled GEMM: C[M x NC] = A[M x K] * B[K x NC], all row-major.
// BM=BN=64, BK=32, 256 threads, 4x4 micro-tile per thread.
// K % 32 == 0, NC % 64 == 0 assumed (true here: K in {128,512}, NC in {512,64}).
// ---------------------------------------------------------------------------
__global__ __launch_bounds__(256) void gemm_kernel(
    const float* __restrict__ A, const float* __restrict__ B,
    float* __restrict__ C, int M, int K, int NC) {
    __shared__ float As[32][64];  // [k][m]
    __shared__ float Bs[32][64];  // [k][n]

    const int tid = threadIdx.x;
    const int tx = tid & 15;   // col group (0..15) -> 4 cols each
    const int ty = tid >> 4;   // row group (0..15) -> 4 rows each
    const int bx = blockIdx.x; // over NC/64
    const int by = blockIdx.y; // over ceil(M/64)

    float acc[4][4];
#pragma unroll
    for (int i = 0; i < 4; i++)
#pragma unroll
        for (int j = 0; j < 4; j++) acc[i][j] = 0.f;

    for (int k0 = 0; k0 < K; k0 += 32) {
        // load A tile (64 rows x 32 k), store transposed As[k][row]
#pragma unroll
        for (int p = 0; p < 8; p++) {
            int lin = p * 256 + tid;
            int row = lin >> 5;       // 0..63
            int kk = lin & 31;        // 0..31
            int gr = by * 64 + row;
            float v = (gr < M) ? A[(size_t)gr * K + k0 + kk] : 0.f;
            As[kk][row] = v;
        }
        // load B tile (32 k x 64 cols)
#pragma unroll
        for (int p = 0; p < 8; p++) {
            int lin = p * 256 + tid;
            int kk = lin >> 6;        // 0..31
            int col = lin & 63;       // 0..63
            Bs[kk][col] = B[(size_t)(k0 + kk) * NC + bx * 64 + col];
        }
        __syncthreads();
#pragma unroll
        for (int kk = 0; kk < 32; kk++) {
            float a[4], b[4];
#pragma unroll
            for (int i = 0; i < 4; i++) a[i] = As[kk][ty * 4 + i];
#pragma unroll
            for (int j = 0; j < 4; j++) b[j] = Bs[kk][tx * 4 + j];
#pragma unroll
            for (int i = 0; i < 4; i++)
#pragma unroll
                for (int j = 0; j < 4; j++) acc[i][j] += a[i] * b[j];
        }
        __syncthreads();
    }

#pragma unroll
    for (int i = 0; i < 4; i++) {
        int gr = by * 64 + ty * 4 + i;
        if (gr < M) {
            size_t base = (size_t)gr * NC + bx * 64 + tx * 4;
#pragma unroll
            for (int j = 0; j < 4; j++) C[base + j] = acc[i][j];
        }
    }
}

// ---------------------------------------------------------------------------
// alpha_self[n,h] = dot(proj[n,h,:], a[h,0:64]); alpha_nb uses a[h,64:128].
// One wave per (n,h) task; lane = f. proj indexed proj[(n*H+h)*64 + f].
// ---------------------------------------------------------------------------
__global__ __launch_bounds__(256) void alpha_kernel(
    const float* __restrict__ proj, const float* __restrict__ a,
    float* __restrict__ as_, float* __restrict__ an_, int NH, int H) {
    int w = blockIdx.x * 4 + (threadIdx.x >> 6);
    int lane = threadIdx.x & 63;
    if (w >= NH) return;
    int h = w % H;
    float p = proj[(size_t)w * 64 + lane];
    float s = p * a[h * 128 + lane];
    float t = p * a[h * 128 + 64 + lane];
#pragma unroll
    for (int off = 32; off > 0; off >>= 1) {
        s += __shfl_down(s, off, 64);
        t += __shfl_down(t, off, 64);
    }
    if (lane == 0) {
        as_[w] = s;
        an_[w] = t;
    }
}

// ---------------------------------------------------------------------------
// denom[d,h] += exp(leaky_relu(as[d,h] + an[s,h])); one thread per edge.
// (segment_max skipped: |e| bounded ~5 by construction, exp safe in fp32;
//  normalized weights are mathematically identical.)
// ---------------------------------------------------------------------------
__global__ __launch_bounds__(256) void edge_denom(
    const int* __restrict__ edges, int E0, const float* __restrict__ as_,
    const float* __restrict__ an_, float* __restrict__ den, int H, int E) {
    int i = blockIdx.x * 256 + threadIdx.x;
    if (i >= E) return;
    int s, d;
    get_edge(edges, E0, i, s, d);
    for (int h = 0; h < H; h++) {
        float e = as_[d * H + h] + an_[s * H + h];
        e = (e > 0.f) ? e : RELU_NEG_SLOPE * e;
        atomicAdd(&den[d * H + h], __expf(e));
    }
}

// ---------------------------------------------------------------------------
// out[d,h,:] += proj[s,h,:] * (exp(e)/den[d,h]); one wave per edge, lane = f.
// ---------------------------------------------------------------------------
__global__ __launch_bounds__(256) void edge_agg(
    const int* __restrict__ edges, int E0, const float* __restrict__ proj,
    const float* __restrict__ as_, const float* __restrict__ an_,
    const float* __restrict__ den, float* __restrict__ out, int H, int E) {
    int i = blockIdx.x * 4 + (threadIdx.x >> 6);
    int lane = threadIdx.x & 63;
    if (i >= E) return;
    int s, d;
    get_edge(edges, E0, i, s, d);
    for (int h = 0; h < H; h++) {
        float e = as_[d * H + h] + an_[s * H + h];
        e = (e > 0.f) ? e : RELU_NEG_SLOPE * e;
        float w = __expf(e) / den[d * H + h];
        float p = proj[((size_t)s * H + h) * 64 + lane];
        atomicAdd(&out[((size_t)d * H + h) * 64 + lane], p * w);
    }
}

// ---------------------------------------------------------------------------
// ELU in place: x>0 ? x : exp(x)-1
// ---------------------------------------------------------------------------
__global__ __launch_bounds__(256) void elu_kernel(float* __restrict__ v, int n) {
    int i = blockIdx.x * 256 + threadIdx.x;
    if (i >= n) return;
    float x = v[i];
    v[i] = (x > 0.f) ? x : (__expf(x) - 1.f);
}

extern "C" void kernel_launch(void* const* d_in, const int* in_sizes, int n_in,
                              void* d_out, int out_size, void* d_ws, size_t ws_size,
                              hipStream_t stream) {
    const float* x  = (const float*)d_in[0];
    const int* edges = (const int*)d_in[1];
    const float* W1 = (const float*)d_in[2];
    const float* a1 = (const float*)d_in[3];
    const float* W2 = (const float*)d_in[4];
    const float* a2 = (const float*)d_in[5];

    const int Din = 128, H1 = 8, F = 64, Dmid = 512;
    const int N = in_sizes[0] / Din;       // 10000
    const int E0 = in_sizes[1] / 2;        // 80000
    const int E = 2 * E0 + N;              // 170000

    float* ws = (float*)d_ws;
    size_t o = 0;
    float* proj1 = ws + o; o += (size_t)N * Dmid;       // N x (H1*F)
    float* hbuf  = ws + o; o += (size_t)N * Dmid;       // layer-1 agg / ELU output
    float* bmat1 = ws + o; o += (size_t)Din * Dmid;     // W1 reshaped to 128x512
    float* as1   = ws + o; o += (size_t)N * H1;
    float* an1   = ws + o; o += (size_t)N * H1;
    float* den1  = ws + o; o += (size_t)N * H1;
    float* proj2 = ws + o; o += (size_t)N * F;
    float* as2   = ws + o; o += (size_t)N;
    float* an2   = ws + o; o += (size_t)N;
    float* den2  = ws + o; o += (size_t)N;

    // zero-init accumulators (ws/d_out are poisoned 0xAA before every launch)
    hipMemsetAsync(hbuf, 0, (size_t)N * Dmid * sizeof(float), stream);
    hipMemsetAsync(den1, 0, (size_t)N * H1 * sizeof(float), stream);
    hipMemsetAsync(den2, 0, (size_t)N * sizeof(float), stream);
    hipMemsetAsync(d_out, 0, (size_t)N * F * sizeof(float), stream);

    // ---- layer 1 ----
    transform_w1<<<(Din * Dmid + 255) / 256, 256, 0, stream>>>(W1, bmat1, Din * Dmid);

    dim3 g1(Dmid / 64, (N + 63) / 64);
    gemm_kernel<<<g1, 256, 0, stream>>>(x, bmat1, proj1, N, Din, Dmid);

    int NH1 = N * H1;
    alpha_kernel<<<(NH1 + 3) / 4, 256, 0, stream>>>(proj1, a1, as1, an1, NH1, H1);

    edge_denom<<<(E + 255) / 256, 256, 0, stream>>>(edges, E0, as1, an1, den1, H1, E);
    edge_agg<<<(E + 3) / 4, 256, 0, stream>>>(edges, E0, proj1, as1, an1, den1,
                                              hbuf, H1, E);

    elu_kernel<<<((size_t)N * Dmid + 255) / 256, 256, 0, stream>>>(hbuf, N * Dmid);

    // ---- layer 2 ----  (W2 is (1,512,64) == row-major 512x64 already)
    dim3 g2(F / 64, (N + 63) / 64);
    gemm_kernel<<<g2, 256, 0, stream>>>(hbuf, W2, proj2, N, Dmid, F);

    alpha_kernel<<<(N + 3) / 4, 256, 0, stream>>>(proj2, a2, as2, an2, N, 1);

    edge_denom<<<(E + 255) / 256, 256, 0, stream>>>(edges, E0, as2, an2, den2, 1, E);
    edge_agg<<<(E + 3) / 4, 256, 0, stream>>>(edges, E0, proj2, as2, an2, den2,
                                              (float*)d_out, 1, E);
}

// Round 2
// 369.187 us; speedup vs baseline: 1.6297x; 1.6297x over previous
//
#include <hip/hip_runtime.h>
#include <hip/hip_bf16.h>

#define RELU_NEG_SLOPE 0.2f

// ---------------------------------------------------------------------------
// Edge decode: src = concat(e0, e1, arange), dst = concat(e1, e0, arange)
// ---------------------------------------------------------------------------
__device__ __forceinline__ void get_edge(const int* __restrict__ edges, int E0,
                                         int i, int& s, int& d) {
    if (i < 2 * E0) {
        s = edges[i];
        d = (i < E0) ? edges[E0 + i] : edges[i - E0];
    } else {
        s = d = i - 2 * E0;
    }
}

// ---------------------------------------------------------------------------
// B[d*512 + h*64 + f] = W1[h][d][f]  (W1 is (8,128,64) row-major)
// ---------------------------------------------------------------------------
__global__ void transform_w1(const float* __restrict__ W1, float* __restrict__ B,
                             int total) {
    int i = blockIdx.x * 256 + threadIdx.x;
    if (i >= total) return;
    int f = i & 63;
    int d = (i >> 6) & 127;
    int h = i >> 13;
    B[d * 512 + h * 64 + f] = W1[i];
}

// ---------------------------------------------------------------------------
// Generic fp32 tiled GEMM: C[M x NC] = A[M x K] * B[K x NC], all row-major.
// BM=BN=64, BK=32, 256 threads, 4x4 micro-tile per thread.
// ---------------------------------------------------------------------------
__global__ __launch_bounds__(256) void gemm_kernel(
    const float* __restrict__ A, const float* __restrict__ B,
    float* __restrict__ C, int M, int K, int NC) {
    __shared__ float As[32][64];  // [k][m]
    __shared__ float Bs[32][64];  // [k][n]

    const int tid = threadIdx.x;
    const int tx = tid & 15;
    const int ty = tid >> 4;
    const int bx = blockIdx.x;
    const int by = blockIdx.y;

    float acc[4][4];
#pragma unroll
    for (int i = 0; i < 4; i++)
#pragma unroll
        for (int j = 0; j < 4; j++) acc[i][j] = 0.f;

    for (int k0 = 0; k0 < K; k0 += 32) {
#pragma unroll
        for (int p = 0; p < 8; p++) {
            int lin = p * 256 + tid;
            int row = lin >> 5;
            int kk = lin & 31;
            int gr = by * 64 + row;
            float v = (gr < M) ? A[(size_t)gr * K + k0 + kk] : 0.f;
            As[kk][row] = v;
        }
#pragma unroll
        for (int p = 0; p < 8; p++) {
            int lin = p * 256 + tid;
            int kk = lin >> 6;
            int col = lin & 63;
            Bs[kk][col] = B[(size_t)(k0 + kk) * NC + bx * 64 + col];
        }
        __syncthreads();
#pragma unroll
        for (int kk = 0; kk < 32; kk++) {
            float a[4], b[4];
#pragma unroll
            for (int i = 0; i < 4; i++) a[i] = As[kk][ty * 4 + i];
#pragma unroll
            for (int j = 0; j < 4; j++) b[j] = Bs[kk][tx * 4 + j];
#pragma unroll
            for (int i = 0; i < 4; i++)
#pragma unroll
                for (int j = 0; j < 4; j++) acc[i][j] += a[i] * b[j];
        }
        __syncthreads();
    }

#pragma unroll
    for (int i = 0; i < 4; i++) {
        int gr = by * 64 + ty * 4 + i;
        if (gr < M) {
            size_t base = (size_t)gr * NC + bx * 64 + tx * 4;
#pragma unroll
            for (int j = 0; j < 4; j++) C[base + j] = acc[i][j];
        }
    }
}

// ---------------------------------------------------------------------------
// alpha_self[n,h] = dot(proj[n,h,:], a[h,0:64]); alpha_nb uses a[h,64:128].
// One wave per (n,h); lane = f.
// ---------------------------------------------------------------------------
__global__ __launch_bounds__(256) void alpha_kernel(
    const float* __restrict__ proj, const float* __restrict__ a,
    float* __restrict__ as_, float* __restrict__ an_, int NH, int H) {
    int w = blockIdx.x * 4 + (threadIdx.x >> 6);
    int lane = threadIdx.x & 63;
    if (w >= NH) return;
    int h = w % H;
    float p = proj[(size_t)w * 64 + lane];
    float s = p * a[h * 128 + lane];
    float t = p * a[h * 128 + 64 + lane];
#pragma unroll
    for (int off = 32; off > 0; off >>= 1) {
        s += __shfl_down(s, off, 64);
        t += __shfl_down(t, off, 64);
    }
    if (lane == 0) {
        as_[w] = s;
        an_[w] = t;
    }
}

// ---------------------------------------------------------------------------
// CSR build step 1: histogram of dst.
// ---------------------------------------------------------------------------
__global__ __launch_bounds__(256) void hist_kernel(
    const int* __restrict__ edges, int E0, int E, int* __restrict__ cnt) {
    int i = blockIdx.x * 256 + threadIdx.x;
    if (i >= E) return;
    int s, d;
    get_edge(edges, E0, i, s, d);
    atomicAdd(&cnt[d], 1);
}

// ---------------------------------------------------------------------------
// CSR build step 2: exclusive scan of cnt -> rowptr (single block, 1024 thr).
// ---------------------------------------------------------------------------
__global__ __launch_bounds__(1024) void scan_kernel(
    const int* __restrict__ cnt, int* __restrict__ rowptr, int N) {
    __shared__ int sums[1024];
    const int t = threadIdx.x;
    const int chunk = (N + 1023) / 1024;
    int begin = t * chunk;
    int end = begin + chunk;
    if (end > N) end = N;
    int s = 0;
    for (int i = begin; i < end; i++) s += cnt[i];
    sums[t] = s;
    __syncthreads();
    // Hillis-Steele inclusive scan
    for (int off = 1; off < 1024; off <<= 1) {
        int v = (t >= off) ? sums[t - off] : 0;
        __syncthreads();
        if (t >= off) sums[t] += v;
        __syncthreads();
    }
    int run = sums[t] - s;  // exclusive prefix of this chunk
    for (int i = begin; i < end; i++) {
        rowptr[i] = run;
        run += cnt[i];
    }
    if (t == 1023) rowptr[N] = sums[1023];
}

// ---------------------------------------------------------------------------
// CSR build step 3: scatter src ids into dst buckets.
// ---------------------------------------------------------------------------
__global__ __launch_bounds__(256) void scatter_kernel(
    const int* __restrict__ edges, int E0, int E,
    const int* __restrict__ rowptr, int* __restrict__ cursor,
    int* __restrict__ idx) {
    int i = blockIdx.x * 256 + threadIdx.x;
    if (i >= E) return;
    int s, d;
    get_edge(edges, E0, i, s, d);
    int pos = atomicAdd(&cursor[d], 1);
    idx[rowptr[d] + pos] = s;
}

// ---------------------------------------------------------------------------
// Pull-style fused softmax + aggregation. One wave per (node d, head h):
//   pass 1: den = sum_j exp(leaky(as[d,h]+an[s_j,h]))  (lane-parallel + reduce)
//   pass 2: acc[f] = sum_j w_j * proj[s_j, h, f]        (lane = f)
// Writes out[(d*H+h)*64+f] exactly once. No atomics.
// ---------------------------------------------------------------------------
__global__ __launch_bounds__(256) void agg_node(
    const int* __restrict__ rowptr, const int* __restrict__ idx,
    const float* __restrict__ proj, const float* __restrict__ as_,
    const float* __restrict__ an_, float* __restrict__ out, int H, int NH) {
    int w = blockIdx.x * 4 + (threadIdx.x >> 6);
    int lane = threadIdx.x & 63;
    if (w >= NH) return;
    int d = w / H;
    int h = w - d * H;
    int start = rowptr[d];
    int deg = rowptr[d + 1] - start;
    float asd = as_[d * H + h];

    // pass 1: denominator
    float den = 0.f;
    for (int j = lane; j < deg; j += 64) {
        int s = idx[start + j];
        float e = asd + an_[s * H + h];
        e = (e > 0.f) ? e : RELU_NEG_SLOPE * e;
        den += __expf(e);
    }
#pragma unroll
    for (int off = 32; off > 0; off >>= 1) den += __shfl_down(den, off, 64);
    den = __shfl(den, 0, 64);
    float rden = 1.f / den;

    // pass 2: weighted gather
    float acc = 0.f;
    for (int j = 0; j < deg; j++) {
        int s = idx[start + j];
        float e = asd + an_[s * H + h];
        e = (e > 0.f) ? e : RELU_NEG_SLOPE * e;
        float wgt = __expf(e) * rden;
        acc += wgt * proj[((size_t)s * H + h) * 64 + lane];
    }
    out[(size_t)w * 64 + lane] = acc;
}

// ---------------------------------------------------------------------------
// ELU in place
// ---------------------------------------------------------------------------
__global__ __launch_bounds__(256) void elu_kernel(float* __restrict__ v, int n) {
    int i = blockIdx.x * 256 + threadIdx.x;
    if (i >= n) return;
    float x = v[i];
    v[i] = (x > 0.f) ? x : (__expf(x) - 1.f);
}

extern "C" void kernel_launch(void* const* d_in, const int* in_sizes, int n_in,
                              void* d_out, int out_size, void* d_ws, size_t ws_size,
                              hipStream_t stream) {
    const float* x  = (const float*)d_in[0];
    const int* edges = (const int*)d_in[1];
    const float* W1 = (const float*)d_in[2];
    const float* a1 = (const float*)d_in[3];
    const float* W2 = (const float*)d_in[4];
    const float* a2 = (const float*)d_in[5];

    const int Din = 128, H1 = 8, F = 64, Dmid = 512;
    const int N = in_sizes[0] / Din;       // 10000
    const int E0 = in_sizes[1] / 2;        // 80000
    const int E = 2 * E0 + N;              // 170000

    float* ws = (float*)d_ws;
    size_t o = 0;
    float* proj1 = ws + o; o += (size_t)N * Dmid;
    float* hbuf  = ws + o; o += (size_t)N * Dmid;
    float* bmat1 = ws + o; o += (size_t)Din * Dmid;
    float* as1   = ws + o; o += (size_t)N * H1;
    float* an1   = ws + o; o += (size_t)N * H1;
    float* proj2 = ws + o; o += (size_t)N * F;
    float* as2   = ws + o; o += (size_t)N;
    float* an2   = ws + o; o += (size_t)N;
    int* cnt    = (int*)(ws + o); o += N;
    int* cursor = (int*)(ws + o); o += N;
    int* rowptr = (int*)(ws + o); o += N + 1;
    int* csridx = (int*)(ws + o); o += E;

    // zero-init CSR counters only (everything else is fully overwritten)
    hipMemsetAsync(cnt, 0, N * sizeof(int), stream);
    hipMemsetAsync(cursor, 0, N * sizeof(int), stream);

    // ---- CSR build (shared by both layers) ----
    hist_kernel<<<(E + 255) / 256, 256, 0, stream>>>(edges, E0, E, cnt);
    scan_kernel<<<1, 1024, 0, stream>>>(cnt, rowptr, N);
    scatter_kernel<<<(E + 255) / 256, 256, 0, stream>>>(edges, E0, E, rowptr,
                                                        cursor, csridx);

    // ---- layer 1 ----
    transform_w1<<<(Din * Dmid + 255) / 256, 256, 0, stream>>>(W1, bmat1, Din * Dmid);

    dim3 g1(Dmid / 64, (N + 63) / 64);
    gemm_kernel<<<g1, 256, 0, stream>>>(x, bmat1, proj1, N, Din, Dmid);

    int NH1 = N * H1;
    alpha_kernel<<<(NH1 + 3) / 4, 256, 0, stream>>>(proj1, a1, as1, an1, NH1, H1);

    agg_node<<<(NH1 + 3) / 4, 256, 0, stream>>>(rowptr, csridx, proj1, as1, an1,
                                                hbuf, H1, NH1);

    elu_kernel<<<((size_t)N * Dmid + 255) / 256, 256, 0, stream>>>(hbuf, N * Dmid);

    // ---- layer 2 ---- (W2 is (1,512,64) == row-major 512x64 already)
    dim3 g2(F / 64, (N + 63) / 64);
    gemm_kernel<<<g2, 256, 0, stream>>>(hbuf, W2, proj2, N, Dmid, F);

    alpha_kernel<<<(N + 3) / 4, 256, 0, stream>>>(proj2, a2, as2, an2, N, 1);

    agg_node<<<(N + 3) / 4, 256, 0, stream>>>(rowptr, csridx, proj2, as2, an2,
                                              (float*)d_out, 1, N);
}

// Round 3
// 276.000 us; speedup vs baseline: 2.1799x; 1.3376x over previous
//
#include <hip/hip_runtime.h>
#include <hip/hip_bf16.h>

#define RELU_NEG_SLOPE 0.2f

__device__ __forceinline__ float leaky(float e) {
    return (e > 0.f) ? e : RELU_NEG_SLOPE * e;
}

// ---------------------------------------------------------------------------
// Edge decode: src = concat(e0, e1, arange), dst = concat(e1, e0, arange)
// ---------------------------------------------------------------------------
__device__ __forceinline__ void get_edge(const int* __restrict__ edges, int E0,
                                         int i, int& s, int& d) {
    if (i < 2 * E0) {
        s = edges[i];
        d = (i < E0) ? edges[E0 + i] : edges[i - E0];
    } else {
        s = d = i - 2 * E0;
    }
}

// ---------------------------------------------------------------------------
// B[d*512 + h*64 + f] = W1[h][d][f]  (W1 is (8,128,64) row-major)
// ---------------------------------------------------------------------------
__global__ void transform_w1(const float* __restrict__ W1, float* __restrict__ B,
                             int total) {
    int i = blockIdx.x * 256 + threadIdx.x;
    if (i >= total) return;
    int f = i & 63;
    int d = (i >> 6) & 127;
    int h = i >> 13;
    B[d * 512 + h * 64 + f] = W1[i];
}

// ---------------------------------------------------------------------------
// Generic fp32 tiled GEMM: C[M x NC] = A[M x K] * B[K x NC], all row-major.
// BM=BN=64, BK=32, 256 threads, 4x4 micro-tile per thread.
// ---------------------------------------------------------------------------
__global__ __launch_bounds__(256) void gemm_kernel(
    const float* __restrict__ A, const float* __restrict__ B,
    float* __restrict__ C, int M, int K, int NC) {
    __shared__ float As[32][64];  // [k][m]
    __shared__ float Bs[32][64];  // [k][n]

    const int tid = threadIdx.x;
    const int tx = tid & 15;
    const int ty = tid >> 4;
    const int bx = blockIdx.x;
    const int by = blockIdx.y;

    float acc[4][4];
#pragma unroll
    for (int i = 0; i < 4; i++)
#pragma unroll
        for (int j = 0; j < 4; j++) acc[i][j] = 0.f;

    for (int k0 = 0; k0 < K; k0 += 32) {
#pragma unroll
        for (int p = 0; p < 8; p++) {
            int lin = p * 256 + tid;
            int row = lin >> 5;
            int kk = lin & 31;
            int gr = by * 64 + row;
            float v = (gr < M) ? A[(size_t)gr * K + k0 + kk] : 0.f;
            As[kk][row] = v;
        }
#pragma unroll
        for (int p = 0; p < 8; p++) {
            int lin = p * 256 + tid;
            int kk = lin >> 6;
            int col = lin & 63;
            Bs[kk][col] = B[(size_t)(k0 + kk) * NC + bx * 64 + col];
        }
        __syncthreads();
#pragma unroll
        for (int kk = 0; kk < 32; kk++) {
            float a[4], b[4];
#pragma unroll
            for (int i = 0; i < 4; i++) a[i] = As[kk][ty * 4 + i];
#pragma unroll
            for (int j = 0; j < 4; j++) b[j] = Bs[kk][tx * 4 + j];
#pragma unroll
            for (int i = 0; i < 4; i++)
#pragma unroll
                for (int j = 0; j < 4; j++) acc[i][j] += a[i] * b[j];
        }
        __syncthreads();
    }

#pragma unroll
    for (int i = 0; i < 4; i++) {
        int gr = by * 64 + ty * 4 + i;
        if (gr < M) {
            size_t base = (size_t)gr * NC + bx * 64 + tx * 4;
#pragma unroll
            for (int j = 0; j < 4; j++) C[base + j] = acc[i][j];
        }
    }
}

// ---------------------------------------------------------------------------
// alpha_self[n,h] = dot(proj[n,h,:], a[h,0:64]); alpha_nb uses a[h,64:128].
// One wave per (n,h); lane = f.
// ---------------------------------------------------------------------------
__global__ __launch_bounds__(256) void alpha_kernel(
    const float* __restrict__ proj, const float* __restrict__ a,
    float* __restrict__ as_, float* __restrict__ an_, int NH, int H) {
    int w = blockIdx.x * 4 + (threadIdx.x >> 6);
    int lane = threadIdx.x & 63;
    if (w >= NH) return;
    int h = w % H;
    float p = proj[(size_t)w * 64 + lane];
    float s = p * a[h * 128 + lane];
    float t = p * a[h * 128 + 64 + lane];
#pragma unroll
    for (int off = 32; off > 0; off >>= 1) {
        s += __shfl_down(s, off, 64);
        t += __shfl_down(t, off, 64);
    }
    if (lane == 0) {
        as_[w] = s;
        an_[w] = t;
    }
}

// ---------------------------------------------------------------------------
// CSR build step 1: histogram of dst.
// ---------------------------------------------------------------------------
__global__ __launch_bounds__(256) void hist_kernel(
    const int* __restrict__ edges, int E0, int E, int* __restrict__ cnt) {
    int i = blockIdx.x * 256 + threadIdx.x;
    if (i >= E) return;
    int s, d;
    get_edge(edges, E0, i, s, d);
    atomicAdd(&cnt[d], 1);
}

// ---------------------------------------------------------------------------
// CSR build step 2: exclusive scan of cnt -> rowptr (single block, 1024 thr).
// ---------------------------------------------------------------------------
__global__ __launch_bounds__(1024) void scan_kernel(
    const int* __restrict__ cnt, int* __restrict__ rowptr, int N) {
    __shared__ int sums[1024];
    const int t = threadIdx.x;
    const int chunk = (N + 1023) / 1024;
    int begin = t * chunk;
    int end = begin + chunk;
    if (end > N) end = N;
    int s = 0;
    for (int i = begin; i < end; i++) s += cnt[i];
    sums[t] = s;
    __syncthreads();
    for (int off = 1; off < 1024; off <<= 1) {
        int v = (t >= off) ? sums[t - off] : 0;
        __syncthreads();
        if (t >= off) sums[t] += v;
        __syncthreads();
    }
    int run = sums[t] - s;
    for (int i = begin; i < end; i++) {
        rowptr[i] = run;
        run += cnt[i];
    }
    if (t == 1023) rowptr[N] = sums[1023];
}

// ---------------------------------------------------------------------------
// CSR build step 3: scatter src ids into dst buckets.
// ---------------------------------------------------------------------------
__global__ __launch_bounds__(256) void scatter_kernel(
    const int* __restrict__ edges, int E0, int E,
    const int* __restrict__ rowptr, int* __restrict__ cursor,
    int* __restrict__ idx) {
    int i = blockIdx.x * 256 + threadIdx.x;
    if (i >= E) return;
    int s, d;
    get_edge(edges, E0, i, s, d);
    int pos = atomicAdd(&cursor[d], 1);
    idx[rowptr[d] + pos] = s;
}

// ---------------------------------------------------------------------------
// Pull-style softmax + aggregation, SINGLE merged pass per (node d, head h):
//   acc[f] = sum_j exp(e_j) * proj[s_j, h, f]   (un-normalized)
//   den    = sum_j exp(e_j)                      (identical in every lane)
//   out    = acc / den, optionally ELU'd (layer-1 fusion).
// 4x unrolled for memory-level parallelism; src ids forced onto the scalar
// path via readfirstlane (wave-uniform addresses).
// No segment_max: |e| is bounded (~±5) by construction, exp is safe in fp32
// and normalization makes the result mathematically identical.
// ---------------------------------------------------------------------------
template <bool DO_ELU>
__global__ __launch_bounds__(256) void agg_node(
    const int* __restrict__ rowptr, const int* __restrict__ idx,
    const float* __restrict__ proj, const float* __restrict__ as_,
    const float* __restrict__ an_, float* __restrict__ out, int H, int NH) {
    int w = blockIdx.x * 4 + (threadIdx.x >> 6);
    int lane = threadIdx.x & 63;
    if (w >= NH) return;
    int d = w / H;
    int h = w - d * H;
    int start = rowptr[d];
    int deg = rowptr[d + 1] - start;
    float asd = as_[(size_t)d * H + h];

    float den = 0.f;
    float acc = 0.f;
    int j = 0;
    for (; j + 4 <= deg; j += 4) {
        int s0 = __builtin_amdgcn_readfirstlane(idx[start + j]);
        int s1 = __builtin_amdgcn_readfirstlane(idx[start + j + 1]);
        int s2 = __builtin_amdgcn_readfirstlane(idx[start + j + 2]);
        int s3 = __builtin_amdgcn_readfirstlane(idx[start + j + 3]);
        float e0 = __expf(leaky(asd + an_[s0 * H + h]));
        float e1 = __expf(leaky(asd + an_[s1 * H + h]));
        float e2 = __expf(leaky(asd + an_[s2 * H + h]));
        float e3 = __expf(leaky(asd + an_[s3 * H + h]));
        float p0 = proj[((size_t)s0 * H + h) * 64 + lane];
        float p1 = proj[((size_t)s1 * H + h) * 64 + lane];
        float p2 = proj[((size_t)s2 * H + h) * 64 + lane];
        float p3 = proj[((size_t)s3 * H + h) * 64 + lane];
        den += (e0 + e1) + (e2 + e3);
        acc += e0 * p0;
        acc += e1 * p1;
        acc += e2 * p2;
        acc += e3 * p3;
    }
    for (; j < deg; j++) {
        int s = __builtin_amdgcn_readfirstlane(idx[start + j]);
        float e = __expf(leaky(asd + an_[s * H + h]));
        float p = proj[((size_t)s * H + h) * 64 + lane];
        den += e;
        acc += e * p;
    }
    float r = acc / den;  // deg >= 1 always (self-loop), den > 0
    if (DO_ELU) r = (r > 0.f) ? r : (__expf(r) - 1.f);
    out[(size_t)w * 64 + lane] = r;
}

extern "C" void kernel_launch(void* const* d_in, const int* in_sizes, int n_in,
                              void* d_out, int out_size, void* d_ws, size_t ws_size,
                              hipStream_t stream) {
    const float* x  = (const float*)d_in[0];
    const int* edges = (const int*)d_in[1];
    const float* W1 = (const float*)d_in[2];
    const float* a1 = (const float*)d_in[3];
    const float* W2 = (const float*)d_in[4];
    const float* a2 = (const float*)d_in[5];

    const int Din = 128, H1 = 8, F = 64, Dmid = 512;
    const int N = in_sizes[0] / Din;       // 10000
    const int E0 = in_sizes[1] / 2;        // 80000
    const int E = 2 * E0 + N;              // 170000

    float* ws = (float*)d_ws;
    size_t o = 0;
    float* proj1 = ws + o; o += (size_t)N * Dmid;
    float* hbuf  = ws + o; o += (size_t)N * Dmid;
    float* bmat1 = ws + o; o += (size_t)Din * Dmid;
    float* as1   = ws + o; o += (size_t)N * H1;
    float* an1   = ws + o; o += (size_t)N * H1;
    float* proj2 = ws + o; o += (size_t)N * F;
    float* as2   = ws + o; o += (size_t)N;
    float* an2   = ws + o; o += (size_t)N;
    int* cnt    = (int*)(ws + o); o += N;
    int* cursor = (int*)(ws + o); o += N;
    int* rowptr = (int*)(ws + o); o += N + 1;
    int* csridx = (int*)(ws + o); o += E;

    hipMemsetAsync(cnt, 0, N * sizeof(int), stream);
    hipMemsetAsync(cursor, 0, N * sizeof(int), stream);

    // ---- CSR build (shared by both layers) ----
    hist_kernel<<<(E + 255) / 256, 256, 0, stream>>>(edges, E0, E, cnt);
    scan_kernel<<<1, 1024, 0, stream>>>(cnt, rowptr, N);
    scatter_kernel<<<(E + 255) / 256, 256, 0, stream>>>(edges, E0, E, rowptr,
                                                        cursor, csridx);

    // ---- layer 1 ----
    transform_w1<<<(Din * Dmid + 255) / 256, 256, 0, stream>>>(W1, bmat1, Din * Dmid);

    dim3 g1(Dmid / 64, (N + 63) / 64);
    gemm_kernel<<<g1, 256, 0, stream>>>(x, bmat1, proj1, N, Din, Dmid);

    int NH1 = N * H1;
    alpha_kernel<<<(NH1 + 3) / 4, 256, 0, stream>>>(proj1, a1, as1, an1, NH1, H1);

    // fused softmax-agg + ELU epilogue
    agg_node<true><<<(NH1 + 3) / 4, 256, 0, stream>>>(rowptr, csridx, proj1,
                                                      as1, an1, hbuf, H1, NH1);

    // ---- layer 2 ---- (W2 is (1,512,64) == row-major 512x64 already)
    dim3 g2(F / 64, (N + 63) / 64);
    gemm_kernel<<<g2, 256, 0, stream>>>(hbuf, W2, proj2, N, Dmid, F);

    alpha_kernel<<<(N + 3) / 4, 256, 0, stream>>>(proj2, a2, as2, an2, N, 1);

    agg_node<false><<<(N + 3) / 4, 256, 0, stream>>>(rowptr, csridx, proj2,
                                                     as2, an2, (float*)d_out, 1, N);
}

// Round 4
// 267.033 us; speedup vs baseline: 2.2531x; 1.0336x over previous
//
#include <hip/hip_runtime.h>
#include <hip/hip_bf16.h>

#define RELU_NEG_SLOPE 0.2f

__device__ __forceinline__ float leaky(float e) {
    return (e > 0.f) ? e : RELU_NEG_SLOPE * e;
}

// ---------------------------------------------------------------------------
// Edge decode: src = concat(e0, e1, arange), dst = concat(e1, e0, arange)
// ---------------------------------------------------------------------------
__device__ __forceinline__ void get_edge(const int* __restrict__ edges, int E0,
                                         int i, int& s, int& d) {
    if (i < 2 * E0) {
        s = edges[i];
        d = (i < E0) ? edges[E0 + i] : edges[i - E0];
    } else {
        s = d = i - 2 * E0;
    }
}

// ---------------------------------------------------------------------------
// B[d*512 + h*64 + f] = W1[h][d][f]  (W1 is (8,128,64) row-major)
// ---------------------------------------------------------------------------
__global__ void transform_w1(const float* __restrict__ W1, float* __restrict__ B,
                             int total) {
    int i = blockIdx.x * 256 + threadIdx.x;
    if (i >= total) return;
    int f = i & 63;
    int d = (i >> 6) & 127;
    int h = i >> 13;
    B[d * 512 + h * 64 + f] = W1[i];
}

// ---------------------------------------------------------------------------
// Generic fp32 tiled GEMM: C[M x NC] = A[M x K] * B[K x NC], all row-major.
// BM=BN=64, BK=32, 256 threads, 4x4 micro-tile per thread.
// ---------------------------------------------------------------------------
__global__ __launch_bounds__(256) void gemm_kernel(
    const float* __restrict__ A, const float* __restrict__ B,
    float* __restrict__ C, int M, int K, int NC) {
    __shared__ float As[32][64];  // [k][m]
    __shared__ float Bs[32][64];  // [k][n]

    const int tid = threadIdx.x;
    const int tx = tid & 15;
    const int ty = tid >> 4;
    const int bx = blockIdx.x;
    const int by = blockIdx.y;

    float acc[4][4];
#pragma unroll
    for (int i = 0; i < 4; i++)
#pragma unroll
        for (int j = 0; j < 4; j++) acc[i][j] = 0.f;

    for (int k0 = 0; k0 < K; k0 += 32) {
#pragma unroll
        for (int p = 0; p < 8; p++) {
            int lin = p * 256 + tid;
            int row = lin >> 5;
            int kk = lin & 31;
            int gr = by * 64 + row;
            float v = (gr < M) ? A[(size_t)gr * K + k0 + kk] : 0.f;
            As[kk][row] = v;
        }
#pragma unroll
        for (int p = 0; p < 8; p++) {
            int lin = p * 256 + tid;
            int kk = lin >> 6;
            int col = lin & 63;
            Bs[kk][col] = B[(size_t)(k0 + kk) * NC + bx * 64 + col];
        }
        __syncthreads();
#pragma unroll
        for (int kk = 0; kk < 32; kk++) {
            float a[4], b[4];
#pragma unroll
            for (int i = 0; i < 4; i++) a[i] = As[kk][ty * 4 + i];
#pragma unroll
            for (int j = 0; j < 4; j++) b[j] = Bs[kk][tx * 4 + j];
#pragma unroll
            for (int i = 0; i < 4; i++)
#pragma unroll
                for (int j = 0; j < 4; j++) acc[i][j] += a[i] * b[j];
        }
        __syncthreads();
    }

#pragma unroll
    for (int i = 0; i < 4; i++) {
        int gr = by * 64 + ty * 4 + i;
        if (gr < M) {
            size_t base = (size_t)gr * NC + bx * 64 + tx * 4;
#pragma unroll
            for (int j = 0; j < 4; j++) C[base + j] = acc[i][j];
        }
    }
}

// ---------------------------------------------------------------------------
// alpha_self[n,h] = dot(proj[n,h,:], a[h,0:64]); alpha_nb uses a[h,64:128].
// One wave per (n,h); lane = f.
// ---------------------------------------------------------------------------
__global__ __launch_bounds__(256) void alpha_kernel(
    const float* __restrict__ proj, const float* __restrict__ a,
    float* __restrict__ as_, float* __restrict__ an_, int NH, int H) {
    int w = blockIdx.x * 4 + (threadIdx.x >> 6);
    int lane = threadIdx.x & 63;
    if (w >= NH) return;
    int h = w % H;
    float p = proj[(size_t)w * 64 + lane];
    float s = p * a[h * 128 + lane];
    float t = p * a[h * 128 + 64 + lane];
#pragma unroll
    for (int off = 32; off > 0; off >>= 1) {
        s += __shfl_down(s, off, 64);
        t += __shfl_down(t, off, 64);
    }
    if (lane == 0) {
        as_[w] = s;
        an_[w] = t;
    }
}

// ---------------------------------------------------------------------------
// CSR build step 1: histogram of dst.
// ---------------------------------------------------------------------------
__global__ __launch_bounds__(256) void hist_kernel(
    const int* __restrict__ edges, int E0, int E, int* __restrict__ cnt) {
    int i = blockIdx.x * 256 + threadIdx.x;
    if (i >= E) return;
    int s, d;
    get_edge(edges, E0, i, s, d);
    atomicAdd(&cnt[d], 1);
}

// ---------------------------------------------------------------------------
// CSR build step 2: exclusive scan of cnt -> rowptr (single block, 1024 thr).
// ---------------------------------------------------------------------------
__global__ __launch_bounds__(1024) void scan_kernel(
    const int* __restrict__ cnt, int* __restrict__ rowptr, int N) {
    __shared__ int sums[1024];
    const int t = threadIdx.x;
    const int chunk = (N + 1023) / 1024;
    int begin = t * chunk;
    int end = begin + chunk;
    if (end > N) end = N;
    int s = 0;
    for (int i = begin; i < end; i++) s += cnt[i];
    sums[t] = s;
    __syncthreads();
    for (int off = 1; off < 1024; off <<= 1) {
        int v = (t >= off) ? sums[t - off] : 0;
        __syncthreads();
        if (t >= off) sums[t] += v;
        __syncthreads();
    }
    int run = sums[t] - s;
    for (int i = begin; i < end; i++) {
        rowptr[i] = run;
        run += cnt[i];
    }
    if (t == 1023) rowptr[N] = sums[1023];
}

// ---------------------------------------------------------------------------
// CSR build step 3: scatter src ids into dst buckets.
// ---------------------------------------------------------------------------
__global__ __launch_bounds__(256) void scatter_kernel(
    const int* __restrict__ edges, int E0, int E,
    const int* __restrict__ rowptr, int* __restrict__ cursor,
    int* __restrict__ idx) {
    int i = blockIdx.x * 256 + threadIdx.x;
    if (i >= E) return;
    int s, d;
    get_edge(edges, E0, i, s, d);
    int pos = atomicAdd(&cursor[d], 1);
    idx[rowptr[d] + pos] = s;
}

// ---------------------------------------------------------------------------
// Pull-style fused softmax + aggregation, one wave per (node d, head h).
// Wave is split into 4 sub-groups of 16 lanes; each sub-group processes a
// DIFFERENT edge per iteration; each lane covers 4 features via float4
// (16 lanes x 16 B = full 64-float proj row). Un-normalized accumulate:
//   acc[f] += exp(e_j) * proj[s_j,h,f],  den += exp(e_j); out = acc/den.
// Epilogue: shuffle-combine the 4 sub-group partials (offsets 16, 32),
// lanes 0-15 write one float4. No atomics, single pass over edges.
// No segment_max: |e| bounded (~±5) by construction -> exp safe in fp32,
// normalization makes the result mathematically identical.
// ---------------------------------------------------------------------------
template <bool DO_ELU>
__global__ __launch_bounds__(256) void agg_node(
    const int* __restrict__ rowptr, const int* __restrict__ idx,
    const float* __restrict__ proj, const float* __restrict__ as_,
    const float* __restrict__ an_, float* __restrict__ out, int H, int NH) {
    int w = blockIdx.x * 4 + (threadIdx.x >> 6);
    int lane = threadIdx.x & 63;
    if (w >= NH) return;
    int sub = lane >> 4;   // which edge slot (0..3)
    int fl = lane & 15;    // feature group: f = fl*4 .. fl*4+3
    int d = w / H;
    int h = w - d * H;
    int start = rowptr[d];
    int deg = rowptr[d + 1] - start;
    float asd = as_[(size_t)d * H + h];

    float4 acc = make_float4(0.f, 0.f, 0.f, 0.f);
    float den = 0.f;
    for (int j0 = 0; j0 < deg; j0 += 4) {
        int j = j0 + sub;
        int jc = (j < deg) ? j : (deg - 1);       // clamp (deg >= 1 always)
        int s = idx[start + jc];
        float e = __expf(leaky(asd + an_[s * H + h]));
        if (j >= deg) e = 0.f;                    // mask tail
        const float4 p = *(const float4*)(proj + ((size_t)(s * H + h) * 64) + fl * 4);
        den += e;
        acc.x += e * p.x;
        acc.y += e * p.y;
        acc.z += e * p.z;
        acc.w += e * p.w;
    }

    // combine the 4 sub-group partials: lane l += lane l+16, l+32, l+48
#pragma unroll
    for (int off = 32; off >= 16; off >>= 1) {
        acc.x += __shfl_down(acc.x, off, 64);
        acc.y += __shfl_down(acc.y, off, 64);
        acc.z += __shfl_down(acc.z, off, 64);
        acc.w += __shfl_down(acc.w, off, 64);
        den += __shfl_down(den, off, 64);
    }

    if (sub == 0) {
        float rden = 1.f / den;
        float4 r;
        r.x = acc.x * rden;
        r.y = acc.y * rden;
        r.z = acc.z * rden;
        r.w = acc.w * rden;
        if (DO_ELU) {
            r.x = (r.x > 0.f) ? r.x : (__expf(r.x) - 1.f);
            r.y = (r.y > 0.f) ? r.y : (__expf(r.y) - 1.f);
            r.z = (r.z > 0.f) ? r.z : (__expf(r.z) - 1.f);
            r.w = (r.w > 0.f) ? r.w : (__expf(r.w) - 1.f);
        }
        *(float4*)(out + (size_t)w * 64 + fl * 4) = r;
    }
}

extern "C" void kernel_launch(void* const* d_in, const int* in_sizes, int n_in,
                              void* d_out, int out_size, void* d_ws, size_t ws_size,
                              hipStream_t stream) {
    const float* x  = (const float*)d_in[0];
    const int* edges = (const int*)d_in[1];
    const float* W1 = (const float*)d_in[2];
    const float* a1 = (const float*)d_in[3];
    const float* W2 = (const float*)d_in[4];
    const float* a2 = (const float*)d_in[5];

    const int Din = 128, H1 = 8, F = 64, Dmid = 512;
    const int N = in_sizes[0] / Din;       // 10000
    const int E0 = in_sizes[1] / 2;        // 80000
    const int E = 2 * E0 + N;              // 170000

    float* ws = (float*)d_ws;
    size_t o = 0;
    float* proj1 = ws + o; o += (size_t)N * Dmid;
    float* hbuf  = ws + o; o += (size_t)N * Dmid;
    float* bmat1 = ws + o; o += (size_t)Din * Dmid;
    float* as1   = ws + o; o += (size_t)N * H1;
    float* an1   = ws + o; o += (size_t)N * H1;
    float* proj2 = ws + o; o += (size_t)N * F;
    float* as2   = ws + o; o += (size_t)N;
    float* an2   = ws + o; o += (size_t)N;
    int* cnt    = (int*)(ws + o); o += N;
    int* cursor = (int*)(ws + o); o += N;
    int* rowptr = (int*)(ws + o); o += N + 1;
    int* csridx = (int*)(ws + o); o += E;

    hipMemsetAsync(cnt, 0, N * sizeof(int), stream);
    hipMemsetAsync(cursor, 0, N * sizeof(int), stream);

    // ---- CSR build (shared by both layers) ----
    hist_kernel<<<(E + 255) / 256, 256, 0, stream>>>(edges, E0, E, cnt);
    scan_kernel<<<1, 1024, 0, stream>>>(cnt, rowptr, N);
    scatter_kernel<<<(E + 255) / 256, 256, 0, stream>>>(edges, E0, E, rowptr,
                                                        cursor, csridx);

    // ---- layer 1 ----
    transform_w1<<<(Din * Dmid + 255) / 256, 256, 0, stream>>>(W1, bmat1, Din * Dmid);

    dim3 g1(Dmid / 64, (N + 63) / 64);
    gemm_kernel<<<g1, 256, 0, stream>>>(x, bmat1, proj1, N, Din, Dmid);

    int NH1 = N * H1;
    alpha_kernel<<<(NH1 + 3) / 4, 256, 0, stream>>>(proj1, a1, as1, an1, NH1, H1);

    // fused softmax-agg + ELU epilogue
    agg_node<true><<<(NH1 + 3) / 4, 256, 0, stream>>>(rowptr, csridx, proj1,
                                                      as1, an1, hbuf, H1, NH1);

    // ---- layer 2 ---- (W2 is (1,512,64) == row-major 512x64 already)
    dim3 g2(F / 64, (N + 63) / 64);
    gemm_kernel<<<g2, 256, 0, stream>>>(hbuf, W2, proj2, N, Dmid, F);

    alpha_kernel<<<(N + 3) / 4, 256, 0, stream>>>(proj2, a2, as2, an2, N, 1);

    agg_node<false><<<(N + 3) / 4, 256, 0, stream>>>(rowptr, csridx, proj2,
                                                     as2, an2, (float*)d_out, 1, N);
}

// Round 5
// 221.867 us; speedup vs baseline: 2.7118x; 1.2036x over previous
//
#include <hip/hip_runtime.h>
#include <hip/hip_bf16.h>

#define RELU_NEG_SLOPE 0.2f

__device__ __forceinline__ float leaky(float e) {
    return (e > 0.f) ? e : RELU_NEG_SLOPE * e;
}

// ---------------------------------------------------------------------------
// Edge decode: src = concat(e0, e1, arange), dst = concat(e1, e0, arange)
// ---------------------------------------------------------------------------
__device__ __forceinline__ void get_edge(const int* __restrict__ edges, int E0,
                                         int i, int& s, int& d) {
    if (i < 2 * E0) {
        s = edges[i];
        d = (i < E0) ? edges[E0 + i] : edges[i - E0];
    } else {
        s = d = i - 2 * E0;
    }
}

// ---------------------------------------------------------------------------
// B[d*512 + h*64 + f] = W1[h][d][f]  (W1 is (8,128,64) row-major)
// ---------------------------------------------------------------------------
__global__ void transform_w1(const float* __restrict__ W1, float* __restrict__ B,
                             int total) {
    int i = blockIdx.x * 256 + threadIdx.x;
    if (i >= total) return;
    int f = i & 63;
    int d = (i >> 6) & 127;
    int h = i >> 13;
    B[d * 512 + h * 64 + f] = W1[i];
}

// ---------------------------------------------------------------------------
// fp32 tiled GEMM with optional split-K.
// C_z[M x NC] = A[M x K(range z)] * B[K x NC], all row-major.
// Block z covers k in [z*KS, (z+1)*KS); output written to C + z*M*NC.
// BM=BN=64, BK=32, 256 threads, 4x4 micro-tile.
// LDS padded to stride 68 floats (272 B): As-store conflicts drop from
// 32-way to 4-way; 272 % 16 == 0 keeps float4 (ds_read_b128) reads aligned
// and conflict-free (a: 4 distinct banksets; b: 2-way broadcast = free).
// ---------------------------------------------------------------------------
__global__ __launch_bounds__(256) void gemm_kernel(
    const float* __restrict__ A, const float* __restrict__ B,
    float* __restrict__ C, int M, int K, int NC, int KS) {
    __shared__ float As[32][68];  // [k][m], padded
    __shared__ float Bs[32][68];  // [k][n], padded

    const int tid = threadIdx.x;
    const int tx = tid & 15;
    const int ty = tid >> 4;
    const int bx = blockIdx.x;
    const int by = blockIdx.y;
    const int kbeg = blockIdx.z * KS;

    float acc[4][4];
#pragma unroll
    for (int i = 0; i < 4; i++)
#pragma unroll
        for (int j = 0; j < 4; j++) acc[i][j] = 0.f;

    for (int k0 = kbeg; k0 < kbeg + KS; k0 += 32) {
#pragma unroll
        for (int p = 0; p < 8; p++) {
            int lin = p * 256 + tid;
            int row = lin >> 5;
            int kk = lin & 31;
            int gr = by * 64 + row;
            float v = (gr < M) ? A[(size_t)gr * K + k0 + kk] : 0.f;
            As[kk][row] = v;
        }
#pragma unroll
        for (int p = 0; p < 8; p++) {
            int lin = p * 256 + tid;
            int kk = lin >> 6;
            int col = lin & 63;
            Bs[kk][col] = B[(size_t)(k0 + kk) * NC + bx * 64 + col];
        }
        __syncthreads();
#pragma unroll
        for (int kk = 0; kk < 32; kk++) {
            float4 av = *(const float4*)&As[kk][ty * 4];
            float4 bv = *(const float4*)&Bs[kk][tx * 4];
            acc[0][0] += av.x * bv.x; acc[0][1] += av.x * bv.y;
            acc[0][2] += av.x * bv.z; acc[0][3] += av.x * bv.w;
            acc[1][0] += av.y * bv.x; acc[1][1] += av.y * bv.y;
            acc[1][2] += av.y * bv.z; acc[1][3] += av.y * bv.w;
            acc[2][0] += av.z * bv.x; acc[2][1] += av.z * bv.y;
            acc[2][2] += av.z * bv.z; acc[2][3] += av.z * bv.w;
            acc[3][0] += av.w * bv.x; acc[3][1] += av.w * bv.y;
            acc[3][2] += av.w * bv.z; acc[3][3] += av.w * bv.w;
        }
        __syncthreads();
    }

    float* Cz = C + (size_t)blockIdx.z * M * NC;
#pragma unroll
    for (int i = 0; i < 4; i++) {
        int gr = by * 64 + ty * 4 + i;
        if (gr < M) {
            float4 r = make_float4(acc[i][0], acc[i][1], acc[i][2], acc[i][3]);
            *(float4*)(Cz + (size_t)gr * NC + bx * 64 + tx * 4) = r;
        }
    }
}

// ---------------------------------------------------------------------------
// out[i] = sum_z part[z*MN + i], 8 slabs, float4 per thread.
// ---------------------------------------------------------------------------
__global__ __launch_bounds__(256) void reduce8(
    const float4* __restrict__ part, float4* __restrict__ out, int MN4) {
    int i = blockIdx.x * 256 + threadIdx.x;
    if (i >= MN4) return;
    float4 s = part[i];
#pragma unroll
    for (int z = 1; z < 8; z++) {
        float4 v = part[(size_t)z * MN4 + i];
        s.x += v.x; s.y += v.y; s.z += v.z; s.w += v.w;
    }
    out[i] = s;
}

// ---------------------------------------------------------------------------
// alpha_self[n,h] = dot(proj[n,h,:], a[h,0:64]); alpha_nb uses a[h,64:128].
// One wave per (n,h); lane = f.
// ---------------------------------------------------------------------------
__global__ __launch_bounds__(256) void alpha_kernel(
    const float* __restrict__ proj, const float* __restrict__ a,
    float* __restrict__ as_, float* __restrict__ an_, int NH, int H) {
    int w = blockIdx.x * 4 + (threadIdx.x >> 6);
    int lane = threadIdx.x & 63;
    if (w >= NH) return;
    int h = w % H;
    float p = proj[(size_t)w * 64 + lane];
    float s = p * a[h * 128 + lane];
    float t = p * a[h * 128 + 64 + lane];
#pragma unroll
    for (int off = 32; off > 0; off >>= 1) {
        s += __shfl_down(s, off, 64);
        t += __shfl_down(t, off, 64);
    }
    if (lane == 0) {
        as_[w] = s;
        an_[w] = t;
    }
}

// ---------------------------------------------------------------------------
// CSR build step 1: histogram of dst.
// ---------------------------------------------------------------------------
__global__ __launch_bounds__(256) void hist_kernel(
    const int* __restrict__ edges, int E0, int E, int* __restrict__ cnt) {
    int i = blockIdx.x * 256 + threadIdx.x;
    if (i >= E) return;
    int s, d;
    get_edge(edges, E0, i, s, d);
    atomicAdd(&cnt[d], 1);
}

// ---------------------------------------------------------------------------
// CSR build step 2: exclusive scan of cnt -> rowptr (single block, 1024 thr).
// ---------------------------------------------------------------------------
__global__ __launch_bounds__(1024) void scan_kernel(
    const int* __restrict__ cnt, int* __restrict__ rowptr, int N) {
    __shared__ int sums[1024];
    const int t = threadIdx.x;
    const int chunk = (N + 1023) / 1024;
    int begin = t * chunk;
    int end = begin + chunk;
    if (end > N) end = N;
    int s = 0;
    for (int i = begin; i < end; i++) s += cnt[i];
    sums[t] = s;
    __syncthreads();
    for (int off = 1; off < 1024; off <<= 1) {
        int v = (t >= off) ? sums[t - off] : 0;
        __syncthreads();
        if (t >= off) sums[t] += v;
        __syncthreads();
    }
    int run = sums[t] - s;
    for (int i = begin; i < end; i++) {
        rowptr[i] = run;
        run += cnt[i];
    }
    if (t == 1023) rowptr[N] = sums[1023];
}

// ---------------------------------------------------------------------------
// CSR build step 3: scatter src ids into dst buckets.
// ---------------------------------------------------------------------------
__global__ __launch_bounds__(256) void scatter_kernel(
    const int* __restrict__ edges, int E0, int E,
    const int* __restrict__ rowptr, int* __restrict__ cursor,
    int* __restrict__ idx) {
    int i = blockIdx.x * 256 + threadIdx.x;
    if (i >= E) return;
    int s, d;
    get_edge(edges, E0, i, s, d);
    int pos = atomicAdd(&cursor[d], 1);
    idx[rowptr[d] + pos] = s;
}

// ---------------------------------------------------------------------------
// Pull-style fused softmax + aggregation, one wave per (node d, head h).
// 4 sub-groups of 16 lanes; each sub-group a different edge per iteration;
// each lane covers 4 features via float4. Un-normalized accumulate, divide
// at end; shuffle-combine partials; lanes 0-15 write one float4.
// No segment_max: |e| bounded (~±5) by construction -> exp safe in fp32.
// ---------------------------------------------------------------------------
template <bool DO_ELU>
__global__ __launch_bounds__(256) void agg_node(
    const int* __restrict__ rowptr, const int* __restrict__ idx,
    const float* __restrict__ proj, const float* __restrict__ as_,
    const float* __restrict__ an_, float* __restrict__ out, int H, int NH) {
    int w = blockIdx.x * 4 + (threadIdx.x >> 6);
    int lane = threadIdx.x & 63;
    if (w >= NH) return;
    int sub = lane >> 4;
    int fl = lane & 15;
    int d = w / H;
    int h = w - d * H;
    int start = rowptr[d];
    int deg = rowptr[d + 1] - start;
    float asd = as_[(size_t)d * H + h];

    float4 acc = make_float4(0.f, 0.f, 0.f, 0.f);
    float den = 0.f;
    for (int j0 = 0; j0 < deg; j0 += 4) {
        int j = j0 + sub;
        int jc = (j < deg) ? j : (deg - 1);
        int s = idx[start + jc];
        float e = __expf(leaky(asd + an_[s * H + h]));
        if (j >= deg) e = 0.f;
        const float4 p = *(const float4*)(proj + ((size_t)(s * H + h) * 64) + fl * 4);
        den += e;
        acc.x += e * p.x;
        acc.y += e * p.y;
        acc.z += e * p.z;
        acc.w += e * p.w;
    }

#pragma unroll
    for (int off = 32; off >= 16; off >>= 1) {
        acc.x += __shfl_down(acc.x, off, 64);
        acc.y += __shfl_down(acc.y, off, 64);
        acc.z += __shfl_down(acc.z, off, 64);
        acc.w += __shfl_down(acc.w, off, 64);
        den += __shfl_down(den, off, 64);
    }

    if (sub == 0) {
        float rden = 1.f / den;
        float4 r;
        r.x = acc.x * rden;
        r.y = acc.y * rden;
        r.z = acc.z * rden;
        r.w = acc.w * rden;
        if (DO_ELU) {
            r.x = (r.x > 0.f) ? r.x : (__expf(r.x) - 1.f);
            r.y = (r.y > 0.f) ? r.y : (__expf(r.y) - 1.f);
            r.z = (r.z > 0.f) ? r.z : (__expf(r.z) - 1.f);
            r.w = (r.w > 0.f) ? r.w : (__expf(r.w) - 1.f);
        }
        *(float4*)(out + (size_t)w * 64 + fl * 4) = r;
    }
}

extern "C" void kernel_launch(void* const* d_in, const int* in_sizes, int n_in,
                              void* d_out, int out_size, void* d_ws, size_t ws_size,
                              hipStream_t stream) {
    const float* x  = (const float*)d_in[0];
    const int* edges = (const int*)d_in[1];
    const float* W1 = (const float*)d_in[2];
    const float* a1 = (const float*)d_in[3];
    const float* W2 = (const float*)d_in[4];
    const float* a2 = (const float*)d_in[5];

    const int Din = 128, H1 = 8, F = 64, Dmid = 512;
    const int N = in_sizes[0] / Din;       // 10000
    const int E0 = in_sizes[1] / 2;        // 80000
    const int E = 2 * E0 + N;              // 170000

    float* ws = (float*)d_ws;
    size_t o = 0;
    float* proj1 = ws + o; o += (size_t)N * Dmid;   // aliased later by gemm2 partials
    float* hbuf  = ws + o; o += (size_t)N * Dmid;
    float* bmat1 = ws + o; o += (size_t)Din * Dmid;
    float* as1   = ws + o; o += (size_t)N * H1;
    float* an1   = ws + o; o += (size_t)N * H1;
    float* proj2 = ws + o; o += (size_t)N * F;
    float* as2   = ws + o; o += (size_t)N;
    float* an2   = ws + o; o += (size_t)N;
    int* cnt    = (int*)(ws + o); o += N;
    int* cursor = (int*)(ws + o); o += N;
    int* rowptr = (int*)(ws + o); o += N + 1;
    int* csridx = (int*)(ws + o); o += E;

    // gemm2 split-K partials: 8 * N * F floats == N * Dmid floats exactly.
    // proj1 is dead once agg_node<true> has produced hbuf -> safe alias.
    float* partials = proj1;

    hipMemsetAsync(cnt, 0, N * sizeof(int), stream);
    hipMemsetAsync(cursor, 0, N * sizeof(int), stream);

    // ---- CSR build (shared by both layers) ----
    hist_kernel<<<(E + 255) / 256, 256, 0, stream>>>(edges, E0, E, cnt);
    scan_kernel<<<1, 1024, 0, stream>>>(cnt, rowptr, N);
    scatter_kernel<<<(E + 255) / 256, 256, 0, stream>>>(edges, E0, E, rowptr,
                                                        cursor, csridx);

    // ---- layer 1 ----
    transform_w1<<<(Din * Dmid + 255) / 256, 256, 0, stream>>>(W1, bmat1, Din * Dmid);

    dim3 g1(Dmid / 64, (N + 63) / 64, 1);
    gemm_kernel<<<g1, 256, 0, stream>>>(x, bmat1, proj1, N, Din, Dmid, Din);

    int NH1 = N * H1;
    alpha_kernel<<<(NH1 + 3) / 4, 256, 0, stream>>>(proj1, a1, as1, an1, NH1, H1);

    agg_node<true><<<(NH1 + 3) / 4, 256, 0, stream>>>(rowptr, csridx, proj1,
                                                      as1, an1, hbuf, H1, NH1);

    // ---- layer 2 ---- (W2 is (1,512,64) == row-major 512x64; split-K=8)
    dim3 g2(F / 64, (N + 63) / 64, 8);
    gemm_kernel<<<g2, 256, 0, stream>>>(hbuf, W2, partials, N, Dmid, F, Dmid / 8);

    int MN4 = N * F / 4;
    reduce8<<<(MN4 + 255) / 256, 256, 0, stream>>>((const float4*)partials,
                                                   (float4*)proj2, MN4);

    alpha_kernel<<<(N + 3) / 4, 256, 0, stream>>>(proj2, a2, as2, an2, N, 1);

    agg_node<false><<<(N + 3) / 4, 256, 0, stream>>>(rowptr, csridx, proj2,
                                                     as2, an2, (float*)d_out, 1, N);
}